// Round 10
// baseline (1477.260 us; speedup 1.0000x reference)
//
#include <hip/hip_runtime.h>

// BiLSTM + partial-CRF loss, MI355X (gfx950).
// R17: recovery + fill internalization. R16's dual-chain interleave NaN'd
// (canary reached MFMAs -> retry budget exhausted somewhere; defect not
// identifiable by inspection) -> recurrence reverted to R15-VERBATIM
// (945us proven: head-issued sc1 polls, fast sc1 x8 + guard sc0sc1 x4096
// tiers, two __syncthreads, single pre4).
// New: the 67MB canary fill moves INSIDE k_lstm. Evidence: canary-era
// "rest" was a constant ~520us vs flag-era 325us across FOUR fill
// implementations (R10 kernel / R11 kernel / R13 fused / R15 memset),
// while the pure store work is ~15us -> the fill DISPATCH path costs
// ~190us. Each wg fills exactly its OWN output region (512 rows x 512B,
// coalesced u64 agent stores; fill and h-store of a row are same-wg
// program-ordered). Cross-wg safety: one-time flag gate (R7-proven):
// __syncthreads() drains each wave's agent stores, tid0 release-stores
// flg[wid]; consumers wait once for their group's 32 flags before the
// loop. Flags zeroed by a 1KB memset (trivial).
// k_crf: R8's register-resident rewrite (validated, absmax 0).
//
// Sizes: B=64, L=512, V=50000, E=256, H=512, T=32.
// Workspace (~84 MiB):
//   x2   bf16 [512*64][256]                16777216 B @ 0
//   H2   bf16 blocked [t][d][g][s][256]    67108864 B @ 16777216
//   em   f32  [512*64][32]                  4194304 B @ 83886080
//   flg  u32  [256 wgs]                        1024 B @ 88080384

#define IMPOSSIBLE -10000.0f
#define CANARY 0x7F7F7F7Fu

typedef __attribute__((ext_vector_type(8))) short bf16x8;
typedef __attribute__((ext_vector_type(4))) float f32x4;
typedef __attribute__((ext_vector_type(4))) unsigned int u32x4;
typedef unsigned int u32;
typedef unsigned short u16;
typedef unsigned long long u64;

__device__ __forceinline__ u16 f2b(float f) {           // fp32 -> bf16 (RNE)
  union { float f; u32 u; } v; v.f = f;
  return (u16)((v.u + 0x7fffu + ((v.u >> 16) & 1u)) >> 16);
}
__device__ __forceinline__ float sigm(float x) { return 1.0f / (1.0f + __expf(-x)); }
__device__ __forceinline__ float tanh_f(float x) { return 1.0f - 2.0f / (__expf(2.0f * x) + 1.0f); }

__device__ __forceinline__ u32 can4(const u32x4& q) {
  return (u32)(q[0] == CANARY) | (u32)(q[1] == CANARY) |
         (u32)(q[2] == CANARY) | (u32)(q[3] == CANARY);
}

// ---------------------------------------------------------------------------
// x2[t*64+b][e] = bf16(emb[sents[b][t]][e]).  One block per t.
__global__ __launch_bounds__(256) void k_embed(
    const int* __restrict__ sents, const float* __restrict__ emb,
    u16* __restrict__ x2) {
  __shared__ int tok[64];
  const int tid = threadIdx.x, t = blockIdx.x;
  if (tid < 64) tok[tid] = sents[tid * 512 + t];
  __syncthreads();
#pragma unroll
  for (int i = 0; i < 16; ++i) {
    const int v = i * 256 + tid;          // float4 index
    const int row = v >> 6, ke = (v & 63) * 4;
    const float4 f = *(const float4*)(emb + (size_t)tok[row] * 256 + ke);
    ushort4 s; s.x = f2b(f.x); s.y = f2b(f.y); s.z = f2b(f.z); s.w = f2b(f.w);
    *(ushort4*)&x2[((size_t)t * 64 + row) * 256 + ke] = s;
  }
}

// ---------------------------------------------------------------------------
// Persistent BiLSTM. 256 wgs x 256 thr, 1 wg/CU. group r=wid&7 -> (d=r>>2,
// g=r&3); slice s=wid>>3 (j0=s*16). Wave wv owns K-quarter for ALL 4 gates.
// Prologue: canary-fill OWN output region (u64 agent stores, coalesced) ->
// barrier (drains stores) -> tid0 release flag -> load weights -> gate on
// group's 32 flags. Per step (R15-verbatim): plain x loads + sc1 poll burst
// -> x MFMAs (overlap flight) -> tied vmcnt(0) + canary check (8 fast sc1
// retries, then proven sc0sc1 guard) -> h MFMAs -> sync -> ds_write pre4 ->
// sync -> reduce + gates -> packed agent h store (no drain, no flag).
__global__ __launch_bounds__(256, 1) void k_lstm(
    const float* __restrict__ Whf, const float* __restrict__ Whb,
    const float* __restrict__ Wif, const float* __restrict__ Wib,
    const float* __restrict__ bf_, const float* __restrict__ bb_,
    const u16* __restrict__ x2, u16* __restrict__ H2, u32* __restrict__ flg) {
  __shared__ float pre4[4096];          // [wv][gate][kh][lm][rr]
  const int tid = threadIdx.x, wid = blockIdx.x;
  const int r = wid & 7, d = r >> 2, g = r & 3, s = wid >> 3;
  const int b0 = g * 16, j0 = s * 16;
  const float* __restrict__ Whh = d ? Whb : Whf;
  const float* __restrict__ Wih = d ? Wib : Wif;
  const float* __restrict__ bias = d ? bb_ : bf_;
  const int wv = tid >> 6, lane = tid & 63, lm = lane & 15, kh = lane >> 4;
  const int bl = tid >> 4, jj = tid & 15;

  // ---- canary-fill OWN output region: rows ((t*2+d)*4+g)*32+s, t=0..511.
  // wave wv covers t in [wv*128, wv*128+128); lane l writes u64 index l of
  // the row (64 lanes x 8B = 512B row, coalesced). Agent scope -> MALL.
  {
    u64* baseq = (u64*)H2;
    const u64 C8 = 0x7F7F7F7F7F7F7F7Full;
#pragma unroll 8
    for (int ti = 0; ti < 128; ++ti) {
      const int t = wv * 128 + ti;
      const size_t row = (((size_t)t * 2 + d) * 4 + g) * 32 + s;
      __hip_atomic_store(baseq + row * 64 + lane, C8, __ATOMIC_RELAXED,
                         __HIP_MEMORY_SCOPE_AGENT);
    }
  }
  __syncthreads();          // drains every wave's fill stores (vmcnt(0))
  if (tid == 0)             // publish: my region is canary-initialized
    __hip_atomic_store(flg + wid, 1u, __ATOMIC_RELEASE,
                       __HIP_MEMORY_SCOPE_AGENT);

  // ---- weight fragments: B[k][n], n=lane&15, k = kh*8+j + 32*kt + wv*Kq ----
  bf16x8 wih_f[8], whh_f[16];
#pragma unroll
  for (int gg = 0; gg < 4; ++gg) {
    const float* wp = Wih + (size_t)(gg * 512 + j0 + lm) * 256 + wv * 64;
#pragma unroll
    for (int kt = 0; kt < 2; ++kt) {
      bf16x8 f;
#pragma unroll
      for (int j = 0; j < 8; ++j) f[j] = (short)f2b(wp[kt * 32 + kh * 8 + j]);
      wih_f[gg * 2 + kt] = f;
    }
    const float* wq = Whh + (size_t)(gg * 512 + j0 + lm) * 512 + wv * 128;
#pragma unroll
    for (int kt = 0; kt < 4; ++kt) {
      bf16x8 f;
#pragma unroll
      for (int j = 0; j < 8; ++j) f[j] = (short)f2b(wq[kt * 32 + kh * 8 + j]);
      whh_f[gg * 4 + kt] = f;
    }
  }
  const float b_i = bias[0 * 512 + j0 + jj];
  const float b_f = bias[1 * 512 + j0 + jj];
  const float b_g = bias[2 * 512 + j0 + jj];
  const float b_o = bias[3 * 512 + j0 + jj];

  // ---- gate: wait until all 32 slice-wgs of my group finished filling ----
  if (tid < 32) {
    int bud = 1 << 22;      // co-residency (1 wg/CU, 256<=256) guarantees
    while (__hip_atomic_load(flg + (tid * 8 + r), __ATOMIC_ACQUIRE,
                             __HIP_MEMORY_SCOPE_AGENT) == 0u && --bud) {}
  }
  __syncthreads();

  float c = 0.f;
  const f32x4 z = {0.f, 0.f, 0.f, 0.f};
#pragma unroll 1
  for (int it = 0; it < 512; ++it) {
    const int tt = d ? (511 - it) : it;
    // x a-frags (K-quarter): issue now, land during the poll
    bf16x8 xa[2];
    {
      const u16* xp = x2 + ((size_t)tt * 64 + b0 + lm) * 256 + wv * 64 + kh * 8;
      xa[0] = *(const bf16x8*)xp;
      xa[1] = *(const bf16x8*)(xp + 32);
    }
    u32x4 q0, q1, q2, q3;
    const u32 *p0 = nullptr, *p1 = nullptr, *p2 = nullptr, *p3 = nullptr;
    if (it > 0) {
      const int tp = d ? (tt + 1) : (tt - 1);
      const size_t tb2 = (((size_t)tp * 2 + d) * 4 + g) * 32;
      const int fo = lm * 16 + (kh & 1) * 8;
      p0 = (const u32*)(H2 + (tb2 + wv * 8 + 0 + (kh >> 1)) * 256 + fo);
      p1 = (const u32*)(H2 + (tb2 + wv * 8 + 2 + (kh >> 1)) * 256 + fo);
      p2 = (const u32*)(H2 + (tb2 + wv * 8 + 4 + (kh >> 1)) * 256 + fo);
      p3 = (const u32*)(H2 + (tb2 + wv * 8 + 6 + (kh >> 1)) * 256 + fo);
      // DEVICE-scope poll burst (sc1): coherent at MALL
      asm volatile(
          "global_load_dwordx4 %0, %4, off sc1\n\t"
          "global_load_dwordx4 %1, %5, off sc1\n\t"
          "global_load_dwordx4 %2, %6, off sc1\n\t"
          "global_load_dwordx4 %3, %7, off sc1"
          : "=&v"(q0), "=&v"(q1), "=&v"(q2), "=&v"(q3)
          : "v"(p0), "v"(p1), "v"(p2), "v"(p3)
          : "memory");
    }
    f32x4 accg[4] = {z, z, z, z};
    // x MFMAs fill the poll flight time
#pragma unroll
    for (int gg = 0; gg < 4; ++gg)
#pragma unroll
      for (int kt = 0; kt < 2; ++kt)
        accg[gg] = __builtin_amdgcn_mfma_f32_16x16x32_bf16(xa[kt], wih_f[gg * 2 + kt], accg[gg], 0, 0, 0);
    if (it > 0) {
      // tied wait: q regs flow through the asm -> check can't hoist above it
      asm volatile("s_waitcnt vmcnt(0)"
                   : "+v"(q0), "+v"(q1), "+v"(q2), "+v"(q3) :: "memory");
      u32 anybad = can4(q0) | can4(q1) | can4(q2) | can4(q3);
      int fast = 8;         // fast tier: device-scope re-polls
      while (__any(anybad != 0) && --fast) {
        asm volatile(
            "global_load_dwordx4 %0, %4, off sc1\n\t"
            "global_load_dwordx4 %1, %5, off sc1\n\t"
            "global_load_dwordx4 %2, %6, off sc1\n\t"
            "global_load_dwordx4 %3, %7, off sc1\n\t"
            "s_waitcnt vmcnt(0)"
            : "=&v"(q0), "=&v"(q1), "=&v"(q2), "=&v"(q3)
            : "v"(p0), "v"(p1), "v"(p2), "v"(p3)
            : "memory");
        anybad = can4(q0) | can4(q1) | can4(q2) | can4(q3);
      }
      if (__any(anybad != 0)) {
        // guard tier: R11-proven loop; on exhaust canary NaNs propagate ->
        // absmax fail (visible, not a hang)
        int bud = 4096;
        do {
          asm volatile(
              "global_load_dwordx4 %0, %4, off sc0 sc1\n\t"
              "global_load_dwordx4 %1, %5, off sc0 sc1\n\t"
              "global_load_dwordx4 %2, %6, off sc0 sc1\n\t"
              "global_load_dwordx4 %3, %7, off sc0 sc1\n\t"
              "s_waitcnt vmcnt(0)"
              : "=&v"(q0), "=&v"(q1), "=&v"(q2), "=&v"(q3)
              : "v"(p0), "v"(p1), "v"(p2), "v"(p3)
              : "memory");
          anybad = can4(q0) | can4(q1) | can4(q2) | can4(q3);
        } while (__any(anybad != 0) && --bud);
      }
      union { u32x4 q; bf16x8 v; } c0, c1, c2, c3;
      c0.q = q0; c1.q = q1; c2.q = q2; c3.q = q3;
#pragma unroll
      for (int gg = 0; gg < 4; ++gg) {
        accg[gg] = __builtin_amdgcn_mfma_f32_16x16x32_bf16(c0.v, whh_f[gg * 4 + 0], accg[gg], 0, 0, 0);
        accg[gg] = __builtin_amdgcn_mfma_f32_16x16x32_bf16(c1.v, whh_f[gg * 4 + 1], accg[gg], 0, 0, 0);
        accg[gg] = __builtin_amdgcn_mfma_f32_16x16x32_bf16(c2.v, whh_f[gg * 4 + 2], accg[gg], 0, 0, 0);
        accg[gg] = __builtin_amdgcn_mfma_f32_16x16x32_bf16(c3.v, whh_f[gg * 4 + 3], accg[gg], 0, 0, 0);
      }
    }
    __syncthreads();        // WAR: prior step's pre4 reads complete
    // partials -> LDS, one ds_write_b128 per gate (layout [wv][g][kh][lm][rr])
#pragma unroll
    for (int gg = 0; gg < 4; ++gg)
      *(f32x4*)&pre4[wv * 1024 + gg * 256 + kh * 64 + lm * 4] = accg[gg];
    __syncthreads();        // RAW: partials visible
    const int off = (bl >> 2) * 64 + jj * 4 + (bl & 3);
    float pi = b_i, pf = b_f, pg = b_g, po = b_o;
#pragma unroll
    for (int w4 = 0; w4 < 4; ++w4) {
      pi += pre4[w4 * 1024 + 0   + off];
      pf += pre4[w4 * 1024 + 256 + off];
      pg += pre4[w4 * 1024 + 512 + off];
      po += pre4[w4 * 1024 + 768 + off];
    }
    c = sigm(pf) * c + sigm(pi) * tanh_f(pg);
    const float h = sigm(po) * tanh_f(c);
    const float hq = __shfl_xor(h, 1);
    if ((tid & 1) == 0) {   // block element = tid; pack pair -> u32, agent store
      const u32 pk = (u32)f2b(h) | ((u32)f2b(hq) << 16);
      u32* hp2 = (u32*)H2 + ((((size_t)tt * 2 + d) * 4 + g) * 32 + s) * 128 + (tid >> 1);
      __hip_atomic_store(hp2, pk, __ATOMIC_RELAXED, __HIP_MEMORY_SCOPE_AGENT);
    }
    // no drain, no flag: consumers poll the data dwords themselves
  }
}

// ---------------------------------------------------------------------------
// em[t*64+b][tag] = [hf|hb] @ W_out^T + b_out. One block per t; blocked-H2 A.
__global__ __launch_bounds__(256) void k_emproj(
    const u16* __restrict__ H2, const float* __restrict__ Wo,
    const float* __restrict__ bo, float* __restrict__ em) {
  __shared__ u16 Wl[32 * 1024];
  const int tid = threadIdx.x, mb = blockIdx.x;
  const int wv = tid >> 6, lane = tid & 63, lm = lane & 15, kh = lane >> 4;
#pragma unroll
  for (int i = 0; i < 32; ++i) {        // stage Wo 32x1024 f32 -> bf16, rotated
    const int row = i, k = tid * 4;
    const float4 f = *(const float4*)(Wo + (size_t)row * 1024 + k);
    ushort4 s; s.x = f2b(f.x); s.y = f2b(f.y); s.z = f2b(f.z); s.w = f2b(f.w);
    *(ushort4*)&Wl[row * 1024 + ((k + 8 * row) & 1023)] = s;
  }
  __syncthreads();
  const f32x4 z = {0.f, 0.f, 0.f, 0.f};
  f32x4 acc[2] = {z, z};
#pragma unroll 2
  for (int kt = 0; kt < 32; ++kt) {     // k-global = kt*32 + kh*8 + j
    const int dd = kt >> 4;
    const int sG = (kt & 15) * 2 + (kh >> 1);
    const u16* ap = H2 + ((((size_t)mb * 2 + dd) * 4 + wv) * 32 + sG) * 256 + lm * 16 + (kh & 1) * 8;
    const bf16x8 a = *(const bf16x8*)ap;
#pragma unroll
    for (int ni = 0; ni < 2; ++ni) {
      const int row = ni * 16 + lm;
      const bf16x8 b = *(const bf16x8*)&Wl[row * 1024 + ((kt * 32 + kh * 8 + 8 * row) & 1023)];
      acc[ni] = __builtin_amdgcn_mfma_f32_16x16x32_bf16(a, b, acc[ni], 0, 0, 0);
    }
  }
#pragma unroll
  for (int ni = 0; ni < 2; ++ni) {
    const int n = ni * 16 + lm;
    const float bv = bo[n];
#pragma unroll
    for (int rr = 0; rr < 4; ++rr) {
      const int m = mb * 64 + wv * 16 + kh * 4 + rr;
      em[(size_t)m * 32 + n] = acc[ni][rr] + bv;
    }
  }
}

// ---------------------------------------------------------------------------
// CRF forward scans, fp32. One wave per (b, which). Register-resident: trans
// rows in 16 regs, alpha propagated via __shfl (no LDS, no barriers),
// possible-tag mask as __ballot bitmask, em/tgt 4-step prefetch pipeline.
__global__ __launch_bounds__(64) void k_crf(
    const float* __restrict__ em, const int* __restrict__ tgt,
    const float* __restrict__ trans, const float* __restrict__ stt,
    const float* __restrict__ ent, float* __restrict__ out) {
  const int lane = threadIdx.x;
  const int b = blockIdx.x >> 1;
  const int isnum = blockIdx.x & 1;
  const int k = lane & 31, j0 = (lane >> 5) * 16;
  float tr[16];
#pragma unroll
  for (int j = 0; j < 16; ++j) tr[j] = trans[(j0 + j) * 32 + k];

  float an; int nxt;
  {
    float a0 = stt[k] + em[(size_t)b * 32 + k];
    int p0 = 1;
    if (isnum) { p0 = tgt[((size_t)b * 512) * 32 + k]; if (p0 == 0) a0 = IMPOSSIBLE; }
    an = a0; nxt = p0;
  }
  u32 cmask = (u32)__ballot(nxt != 0);

  const size_t eb = (size_t)b * 32 + k;        // + t*2048
  const size_t tb = (size_t)b * 16384 + k;     // + t*32
  float e1 = em[eb + 1 * 2048], e2 = em[eb + 2 * 2048];
  float e3 = em[eb + 3 * 2048], e4 = em[eb + 4 * 2048];
  int g1 = 1, g2 = 1, g3 = 1, g4 = 1;
  if (isnum) {
    g1 = tgt[tb + 1 * 32]; g2 = tgt[tb + 2 * 32];
    g3 = tgt[tb + 3 * 32]; g4 = tgt[tb + 4 * 32];
  }

  auto step = [&](float e_raw, int nx) {
    const u32 cm = cmask >> j0;
    float vv[16];
#pragma unroll
    for (int j = 0; j < 16; ++j) {
      const float a = __shfl(an, j0 + j);            // alpha[j0+j], prev step
      float t_ = tr[j];
      if (isnum && ((((cm >> j) & 1u) == 0u) || nx == 0)) t_ = IMPOSSIBLE;
      vv[j] = a + t_;
    }
    const float m0 = fmaxf(fmaxf(fmaxf(vv[0], vv[1]), fmaxf(vv[2], vv[3])),
                           fmaxf(fmaxf(vv[4], vv[5]), fmaxf(vv[6], vv[7])));
    const float m1 = fmaxf(fmaxf(fmaxf(vv[8], vv[9]), fmaxf(vv[10], vv[11])),
                           fmaxf(fmaxf(vv[12], vv[13]), fmaxf(vv[14], vv[15])));
    const float m = fmaxf(m0, m1);                   // fmax tree: exact
    float ss = 0.f;
#pragma unroll
    for (int j = 0; j < 16; ++j) ss += __expf(vv[j] - m);   // same order as R7
    const float m2 = __shfl_xor(m, 32);
    const float s2 = __shfl_xor(ss, 32);
    const float M = fmaxf(m, m2);
    const float S = ss * __expf(m - M) + s2 * __expf(m2 - M);
    const float e = (isnum && nx == 0) ? IMPOSSIBLE : e_raw;
    an = M + __logf(S) + e;
    nxt = nx;
    if (isnum) cmask = (u32)__ballot(nx != 0);
  };

#pragma unroll 1
  for (int t = 1; t <= 505; t += 4) {                // steps t..t+3
    const int t7 = (t + 7 < 512) ? (t + 7) : 511;    // clamp last prefetch
    const float n1 = em[eb + (size_t)(t + 4) * 2048];
    const float n2 = em[eb + (size_t)(t + 5) * 2048];
    const float n3 = em[eb + (size_t)(t + 6) * 2048];
    const float n4 = em[eb + (size_t)t7 * 2048];
    int h1 = 1, h2 = 1, h3 = 1, h4 = 1;
    if (isnum) {
      h1 = tgt[tb + (size_t)(t + 4) * 32]; h2 = tgt[tb + (size_t)(t + 5) * 32];
      h3 = tgt[tb + (size_t)(t + 6) * 32]; h4 = tgt[tb + (size_t)t7 * 32];
    }
    step(e1, g1); step(e2, g2); step(e3, g3); step(e4, g4);
    e1 = n1; e2 = n2; e3 = n3; e4 = n4;
    g1 = h1; g2 = h2; g3 = h3; g4 = h4;
  }
  step(e1, g1); step(e2, g2); step(e3, g3);          // t = 509, 510, 511

  float x;
  if (!isnum) {
    x = an + ent[k];
  } else {
    const float et = ent[k] * (float)nxt;
    x = an + ((et == 0.f) ? IMPOSSIBLE : et);
  }
  float m = x;
#pragma unroll
  for (int o = 1; o < 32; o <<= 1) m = fmaxf(m, __shfl_xor(m, o));
  float ss = __expf(x - m);
#pragma unroll
  for (int o = 1; o < 32; o <<= 1) ss += __shfl_xor(ss, o);
  if (lane == 0) {
    const float rr = m + __logf(ss);
    atomicAdd(out, isnum ? -rr : rr);
  }
}

// ---------------------------------------------------------------------------
extern "C" void kernel_launch(void* const* d_in, const int* in_sizes, int n_in,
                              void* d_out, int out_size, void* d_ws, size_t ws_size,
                              hipStream_t stream) {
  (void)in_sizes; (void)n_in; (void)ws_size;
  const int* sents = (const int*)d_in[0];
  const int* tgt = (const int*)d_in[2];
  const float* emb = (const float*)d_in[3];
  const float* Wif = (const float*)d_in[4];
  const float* Whf = (const float*)d_in[5];
  const float* bf_ = (const float*)d_in[6];
  const float* Wib = (const float*)d_in[7];
  const float* Whb = (const float*)d_in[8];
  const float* bb_ = (const float*)d_in[9];
  const float* Wo = (const float*)d_in[10];
  const float* bo = (const float*)d_in[11];
  const float* stt = (const float*)d_in[12];
  const float* ent = (const float*)d_in[13];
  const float* trans = (const float*)d_in[14];
  float* out = (float*)d_out;

  char* ws = (char*)d_ws;
  u16* x2 = (u16*)ws;                          // 16777216 B
  u16* H2 = (u16*)(ws + 16777216ull);          // 67108864 B (blocked)
  float* em = (float*)(ws + 83886080ull);      //  4194304 B
  u32* flg = (u32*)(ws + 88080384ull);         //     1024 B

  hipMemsetAsync(flg, 0, 1024, stream);                 // fill-done flags
  hipMemsetAsync(d_out, 0, (size_t)out_size, stream);   // out accumulator
  k_embed<<<dim3(512), dim3(256), 0, stream>>>(sents, emb, x2);
  k_lstm<<<dim3(256), dim3(256), 0, stream>>>(Whf, Whb, Wif, Wib, bf_, bb_, x2, H2, flg);
  k_emproj<<<dim3(512), dim3(256), 0, stream>>>(H2, Wo, bo, em);
  k_crf<<<dim3(128), dim3(64), 0, stream>>>(em, tgt, trans, stt, ent, out);
}